// Round 5
// baseline (242.117 us; speedup 1.0000x reference)
//
#include <hip/hip_runtime.h>
#include <cstdint>

// B=512, D=256, H=512. out: [512,512] fp32.
// ws: Ai [512*512] f32 (C2-scaled) | Aj [512*512] f32 ((..+b1)*C2) | W2q [512*512] i8 swizzled
//     | lut1g u8[2048] (i8 127*tanh over u=C2*x in [-9.6,9.6]) | lut2g f32[2048] (sigma over u2 in [-12,12])

#define NB 512
#define ND 256
#define NH 512
#define C2 2.885390081777927f  // 2*log2(e): tanh(x) = 1 - 2/(exp2(x*C2)+1)

// LUT domains (u-space, i.e. already C2-scaled)
#define L1_X0 (-9.6f)
#define L1_S (2048.0f / 19.2f)
#define L1_IS (19.2f / 2048.0f)
#define L2_Y0 (-12.0f)
#define L2_S (2048.0f / 24.0f)
#define L2_IS (24.0f / 2048.0f)

typedef int i32x4 __attribute__((ext_vector_type(4)));
typedef int i32x16 __attribute__((ext_vector_type(16)));
typedef unsigned int u32;
typedef unsigned char u8;

__device__ __forceinline__ float exp2_fast(float x) {
#if __has_builtin(__builtin_amdgcn_exp2f)
  return __builtin_amdgcn_exp2f(x);
#else
  return exp2f(x);
#endif
}
__device__ __forceinline__ float rcp_fast(float x) {
#if __has_builtin(__builtin_amdgcn_rcpf)
  return __builtin_amdgcn_rcpf(x);
#else
  return 1.0f / x;
#endif
}
__device__ __forceinline__ u32 perm_b32(u32 hi, u32 lo, u32 sel) {
#if __has_builtin(__builtin_amdgcn_perm)
  return __builtin_amdgcn_perm(hi, lo, sel);
#else
  u32 r = 0;
  for (int b = 0; b < 4; ++b) {
    const u32 c = (sel >> (8 * b)) & 255;
    const u32 byte = (c < 4) ? (lo >> (8 * c)) & 255 : (c < 8) ? (hi >> (8 * (c - 4))) & 255 : 0;
    r |= byte << (8 * b);
  }
  return r;
#endif
}
// u pre-scaled by C2: float whose low byte = int8(round(127*tanh(u/C2)))
__device__ __forceinline__ u32 tanh_q127_magic(float u) {
  const float r = rcp_fast(exp2_fast(u) + 1.0f);
  return __builtin_bit_cast(u32, fmaf(-254.0f, r, 12583039.0f));
}

// ---------------- prep v4 ----------------
// blocks 0..255: tiled GEMM, block (it,nt) -> Ai/Aj rows i0..i0+31, cols n0..n0+31
// blocks 256..319: W2 -> i8 swizzled frags. block 320: lut1g. block 321: lut2g.
__global__ __launch_bounds__(256) void prep_all(const float* __restrict__ h,
                                                const float* __restrict__ W1,
                                                const float* __restrict__ b1,
                                                const float* __restrict__ W2,
                                                float* __restrict__ Ai,
                                                float* __restrict__ Aj,
                                                u8* __restrict__ W2q,
                                                u8* __restrict__ lut1g,
                                                float* __restrict__ lut2g) {
  const int t = threadIdx.x;
  const int bx = blockIdx.x;
  if (bx < 256) {
    __shared__ float hs[32][68];    // h tile: 32 i x 64 d (padded)
    __shared__ float w1t[64][36];   // W1 rows (d)       x 32 n (padded)
    __shared__ float w1b[64][36];   // W1 rows (256 + d) x 32 n
    const int it = bx >> 4, nt = bx & 15;
    const int i0 = it * 32, n0 = nt * 32;
    const int nn = t & 31, ig = t >> 5;  // thread -> col nn, rows ig*4..ig*4+3
    float accA[4] = {0.f, 0.f, 0.f, 0.f}, accB[4] = {0.f, 0.f, 0.f, 0.f};
    for (int c2 = 0; c2 < 4; ++c2) {
      __syncthreads();
      {  // stage h tile
        const int r = t >> 3, c0 = (t & 7) * 8;
        const float* src = h + (size_t)(i0 + r) * ND + c2 * 64 + c0;
        const float4 a = *(const float4*)src;
        const float4 b = *(const float4*)(src + 4);
        *(float4*)&hs[r][c0] = a;
        *(float4*)&hs[r][c0 + 4] = b;
      }
      {  // stage W1 top/bottom tiles
        const int r = t >> 2, c0 = (t & 3) * 8;
        const float* st = W1 + (size_t)(c2 * 64 + r) * NH + n0 + c0;
        const float* sb = W1 + (size_t)(256 + c2 * 64 + r) * NH + n0 + c0;
        const float4 a = *(const float4*)st;
        const float4 b = *(const float4*)(st + 4);
        const float4 c = *(const float4*)sb;
        const float4 d = *(const float4*)(sb + 4);
        *(float4*)&w1t[r][c0] = a;
        *(float4*)&w1t[r][c0 + 4] = b;
        *(float4*)&w1b[r][c0] = c;
        *(float4*)&w1b[r][c0 + 4] = d;
      }
      __syncthreads();
#pragma unroll 4
      for (int k4 = 0; k4 < 16; ++k4) {
        const float4 hv0 = *(const float4*)&hs[ig * 4 + 0][k4 * 4];
        const float4 hv1 = *(const float4*)&hs[ig * 4 + 1][k4 * 4];
        const float4 hv2 = *(const float4*)&hs[ig * 4 + 2][k4 * 4];
        const float4 hv3 = *(const float4*)&hs[ig * 4 + 3][k4 * 4];
        const float* h0 = (const float*)&hv0;
        const float* h1 = (const float*)&hv1;
        const float* h2 = (const float*)&hv2;
        const float* h3 = (const float*)&hv3;
#pragma unroll
        for (int j = 0; j < 4; ++j) {
          const float wtj = w1t[k4 * 4 + j][nn];
          const float wbj = w1b[k4 * 4 + j][nn];
          accA[0] = fmaf(h0[j], wtj, accA[0]);
          accA[1] = fmaf(h1[j], wtj, accA[1]);
          accA[2] = fmaf(h2[j], wtj, accA[2]);
          accA[3] = fmaf(h3[j], wtj, accA[3]);
          accB[0] = fmaf(h0[j], wbj, accB[0]);
          accB[1] = fmaf(h1[j], wbj, accB[1]);
          accB[2] = fmaf(h2[j], wbj, accB[2]);
          accB[3] = fmaf(h3[j], wbj, accB[3]);
        }
      }
    }
    const float b1n = b1[n0 + nn];
#pragma unroll
    for (int r = 0; r < 4; ++r) {
      Ai[(size_t)(i0 + ig * 4 + r) * NH + n0 + nn] = accA[r] * C2;
      Aj[(size_t)(i0 + ig * 4 + r) * NH + n0 + nn] = (accB[r] + b1n) * C2;
    }
  } else if (bx < 320) {
    // W2 -> i8 (scale 0.25/127), MFMA B-frag order for i8 32x32x32:
    // frag id g = ks*1024 + nt*64 + lane (16 B): byte j = q(W2[ks*32 + (lane>>5)*16 + j][nt*32 + (lane&31)])
    const int g = (bx - 256) * 256 + t;  // 0..16383
    const int lane = g & 63;
    const int nt = (g >> 6) & 15;
    const int ks = g >> 10;
    const int n = nt * 32 + (lane & 31);
    const int kb = ks * 32 + ((lane >> 5) << 4);
    u32 w[4];
#pragma unroll
    for (int q = 0; q < 4; ++q) {
      u32 acc = 0;
#pragma unroll
      for (int j = 0; j < 4; ++j) {
        const float wv = fminf(fmaxf(W2[(kb + q * 4 + j) * NH + n], -0.25f), 0.25f);
        const int qi = (int)rintf(wv * 508.0f);  // 508 = 127/0.25
        acc |= ((u32)(qi & 255)) << (8 * j);
      }
      w[q] = acc;
    }
    ((uint4*)W2q)[g] = make_uint4(w[0], w[1], w[2], w[3]);
  } else if (bx == 320) {
    // lut1: i8(round(127*tanh)) at bin centers u_e = L1_X0 + e*L1_IS
#pragma unroll
    for (int r = 0; r < 8; ++r) {
      const int e = t + r * 256;
      const float u = fmaf((float)e, L1_IS, L1_X0);
      lut1g[e] = (u8)(tanh_q127_magic(u) & 255u);
    }
  } else {
    // lut2: sigma(u2) = 1/(2^u2+1) at bin centers u2_e = L2_Y0 + e*L2_IS
#pragma unroll
    for (int r = 0; r < 8; ++r) {
      const int e = t + r * 256;
      const float u = fmaf((float)e, L2_IS, L2_Y0);
      lut2g[e] = rcp_fast(exp2_fast(u) + 1.0f);
    }
  }
}

// ---------------- main v6: R0 structure, LUT nonlinearities (no per-pair transcendentals) ----------------
// Block: one i, 32 j's, N=512, K=512 (16 ks of 32). 512 thr / 8 waves; wave w: n-tiles {2w,2w+1}.
// Layer-1: i8 tanh via lut1 (2 replicas, lane&1). Layer-2: sigma via lut2 f32.
// Per eval: fma -> med3-clamp -> cvt -> ds_read (4 VALU + 1 DS) instead of exp2+rcp (~36 cy trans).
// Epilogue reduce: 2-level shfl fold -> red2[32][64] -> 512-thread final pass (proven in R3).
__global__ __launch_bounds__(512, 4) void pair_main(const float* __restrict__ Ai,
                                                    const float* __restrict__ Aj,
                                                    const u8* __restrict__ W2q,
                                                    const float* __restrict__ b2,
                                                    const float* __restrict__ W3,
                                                    const float* __restrict__ b3,
                                                    const u8* __restrict__ lut1g,
                                                    const float* __restrict__ lut2g,
                                                    float* __restrict__ out) {
  __shared__ __align__(16) u8 xs[32 * 512];  // 16 KB
  __shared__ __align__(16) u8 lut1[4096];    // 2 replicas x 2048
  __shared__ __align__(16) float lut2[2048]; // 8 KB
  __shared__ float red2[32][64];             // 8 KB
  __shared__ float wsum[8];

  const int t = threadIdx.x;
  const int w = t >> 6;
  const int lane = t & 63;
  const int lhi = lane >> 5;
  const int llo = lane & 31;
  const int bx = blockIdx.x;
  const int i = bx >> 4;
  const int j0 = (bx & 15) * 32;

  // ---- copy LUTs global -> LDS (L2-resident; 12 KB total) ----
  if (t < 128) {
    const uint4 v = ((const uint4*)lut1g)[t];
    ((uint4*)lut1)[t] = v;
    ((uint4*)lut1)[128 + t] = v;  // replica for lane&1
  }
  {
    const uint4 v2 = ((const uint4*)lut2g)[t];
    ((uint4*)lut2)[t] = v2;
  }

  // ---- epilogue invariants ----
  const float SCALE = (0.25f / (127.0f * 127.0f)) * C2;
  const float K1 = SCALE * L2_S;
  const float O2 = 0.5f - L2_Y0 * L2_S;
  float K2[2], w3v[2];
#pragma unroll
  for (int ntl = 0; ntl < 2; ++ntl) {
    const int n = w * 64 + ntl * 32 + llo;
    K2[ntl] = fmaf(b2[n] * C2, L2_S, O2);
    w3v[ntl] = W3[n];
  }
  {
    float w3s = w3v[0] + w3v[1];
#pragma unroll
    for (int off = 1; off < 32; off <<= 1) w3s += __shfl_xor(w3s, off, 64);
    if (lane == 0) wsum[w] = w3s;
  }
  __syncthreads();  // LUTs ready

  // ---- stage X via lut1: thread t -> row = t&31, slots {t>>5, (t>>5)+16} (16 k each) ----
  {
    const int srow = t & 31;
    const int ss0 = t >> 5;  // 0..15
    const int k0 = ss0 * 16;
    const float* ajr = Aj + (size_t)(j0 + srow) * NH;
    const float* air = Ai + (size_t)i * NH;
    const u8* lp = lut1 + ((lane & 1) << 11);
    const float O1 = 0.5f - L1_X0 * L1_S;
#pragma unroll
    for (int uu = 0; uu < 2; ++uu) {
      const int koff = k0 + uu * 256;
      u32 wd[4];
#pragma unroll
      for (int q = 0; q < 4; ++q) {
        const float4 fa = *(const float4*)(ajr + koff + q * 4);
        const float4 ga = *(const float4*)(air + koff + q * 4);
        float us[4] = {fa.x + ga.x, fa.y + ga.y, fa.z + ga.z, fa.w + ga.w};
        u32 m[4];
#pragma unroll
        for (int e = 0; e < 4; ++e) {
          float f = fmaf(us[e], L1_S, O1);
          f = fminf(fmaxf(f, 0.0f), 2047.0f);
          m[e] = lp[(u32)f];
        }
        const u32 p01 = perm_b32(m[1], m[0], 0x0C0C0400u);
        const u32 p23 = perm_b32(m[3], m[2], 0x0C0C0400u);
        wd[q] = perm_b32(p23, p01, 0x05040100u);
      }
      ((uint4*)xs)[(ss0 + uu * 16) * 32 + srow] = make_uint4(wd[0], wd[1], wd[2], wd[3]);
    }
  }
  __syncthreads();

  // ---- K-loop: ping-pong x2 unroll, prefetch distance 2 (unchanged from R0) ----
  i32x16 acc[2];
#pragma unroll
  for (int nt = 0; nt < 2; ++nt)
#pragma unroll
    for (int q = 0; q < 16; ++q) acc[nt][q] = 0;

  const i32x4* xsv = (const i32x4*)xs;
  const int abase = lhi * 32 + llo;                       // + ks*64
  const uint4* w2v = (const uint4*)W2q + w * 128 + lane;  // + ks*1024, +64 for ntl=1

  i32x4 aP0 = xsv[abase];
  i32x4 aP1 = xsv[64 + abase];
  uint4 bP00 = w2v[0], bP01 = w2v[64];
  uint4 bP10 = w2v[1024], bP11 = w2v[1024 + 64];

#pragma unroll
  for (int kk = 0; kk < 8; ++kk) {
    const int ks0 = 2 * kk;
    {
      const i32x4 a = aP0;
      const i32x4 c0 = __builtin_bit_cast(i32x4, bP00);
      const i32x4 c1 = __builtin_bit_cast(i32x4, bP01);
      if (kk < 7) {
        aP0 = xsv[(ks0 + 2) * 64 + abase];
        const uint4* wp = w2v + (ks0 + 2) * 1024;
        bP00 = wp[0];
        bP01 = wp[64];
      }
      acc[0] = __builtin_amdgcn_mfma_i32_32x32x32_i8(a, c0, acc[0], 0, 0, 0);
      acc[1] = __builtin_amdgcn_mfma_i32_32x32x32_i8(a, c1, acc[1], 0, 0, 0);
    }
    {
      const i32x4 a = aP1;
      const i32x4 c0 = __builtin_bit_cast(i32x4, bP10);
      const i32x4 c1 = __builtin_bit_cast(i32x4, bP11);
      if (kk < 7) {
        aP1 = xsv[(ks0 + 3) * 64 + abase];
        const uint4* wp = w2v + (ks0 + 3) * 1024;
        bP10 = wp[0];
        bP11 = wp[64];
      }
      acc[0] = __builtin_amdgcn_mfma_i32_32x32x32_i8(a, c0, acc[0], 0, 0, 0);
      acc[1] = __builtin_amdgcn_mfma_i32_32x32x32_i8(a, c1, acc[1], 0, 0, 0);
    }
  }

  // ---- epilogue via lut2: idx = acc*K1 + K2; r = lut2[idx]; partial = Sum w3*r ----
#pragma unroll
  for (int reg = 0; reg < 16; ++reg) {
    float f0 = fmaf((float)acc[0][reg], K1, K2[0]);
    float f1 = fmaf((float)acc[1][reg], K1, K2[1]);
    f0 = fminf(fmaxf(f0, 0.0f), 2047.0f);
    f1 = fminf(fmaxf(f1, 0.0f), 2047.0f);
    const float r0 = lut2[(u32)f0];
    const float r1 = lut2[(u32)f1];
    float sr = fmaf(w3v[0], r0, w3v[1] * r1);
    sr += __shfl_xor(sr, 1, 64);
    sr += __shfl_xor(sr, 2, 64);
    const int row = (reg & 3) + 8 * (reg >> 2) + 4 * lhi;  // 0..31
    if ((llo & 3) == 0) red2[row][w * 8 + (llo >> 2)] = sr;
  }
  __syncthreads();

  // ---- final reduce: 16 threads per output row ----
  {
    const float w3tot = b3[0] + ((wsum[0] + wsum[1]) + (wsum[2] + wsum[3])) +
                        ((wsum[4] + wsum[5]) + (wsum[6] + wsum[7]));
    const int row = t >> 4;
    const int sub = t & 15;
    const float4 v = *(const float4*)&red2[row][sub * 4];
    float s2 = (v.x + v.y) + (v.z + v.w);
    s2 += __shfl_xor(s2, 1, 16);
    s2 += __shfl_xor(s2, 2, 16);
    s2 += __shfl_xor(s2, 4, 16);
    s2 += __shfl_xor(s2, 8, 16);
    if (sub == 0) {
      const int j = j0 + row;
      out[i * NB + j] = (j == i) ? -20.0f : fmaf(-2.0f, s2, w3tot);
    }
  }
}

extern "C" void kernel_launch(void* const* d_in, const int* in_sizes, int n_in,
                              void* d_out, int out_size, void* d_ws, size_t ws_size,
                              hipStream_t stream) {
  const float* h = (const float*)d_in[0];
  const float* W1 = (const float*)d_in[1];
  const float* b1 = (const float*)d_in[2];
  const float* W2 = (const float*)d_in[3];
  const float* b2 = (const float*)d_in[4];
  const float* W3 = (const float*)d_in[5];
  const float* b3 = (const float*)d_in[6];
  float* out = (float*)d_out;

  float* Ai = (float*)d_ws;
  float* Aj = Ai + NB * NH;
  u8* W2q = (u8*)(Aj + NB * NH);
  u8* lut1g = W2q + NB * NH;
  float* lut2g = (float*)(lut1g + 2048);

  prep_all<<<322, 256, 0, stream>>>(h, W1, b1, W2, Ai, Aj, W2q, lut1g, lut2g);
  pair_main<<<8192, 512, 0, stream>>>(Ai, Aj, W2q, b2, W3, b3, lut1g, lut2g, out);
}